// Round 1
// baseline (488.790 us; speedup 1.0000x reference)
//
#include <hip/hip_runtime.h>
#include <hip/hip_bf16.h>

// ---------------------------------------------------------------------------
// CustomTransformerLayer: QKV proj -> unscaled single-head attn -> Wo -> LN1
//                         -> FF1(relu) -> FF2 -> LN2
// B=4, S=2048, E=1024, FF=4096.  All GEMMs in bf16 MFMA (16x16x32), fp32 acc.
// ---------------------------------------------------------------------------

using u16 = unsigned short;
typedef __attribute__((ext_vector_type(8))) short short8;
typedef __attribute__((ext_vector_type(4))) float f32x4;

#define BATCH 4
#define SEQ   2048
#define EMB   1024
#define FFD   4096

__device__ __forceinline__ u16 f2bf(float f) {
    union { float f; unsigned u; } x{f};
    unsigned r = (x.u + 0x7fffu + ((x.u >> 16) & 1u)) >> 16;
    return (u16)r;
}

typedef const __attribute__((address_space(1))) void* gas_ptr;
typedef __attribute__((address_space(3))) void* las_ptr;

__device__ __forceinline__ void load_lds16(const void* g, void* l) {
    __builtin_amdgcn_global_load_lds((gas_ptr)g, (las_ptr)l, 16, 0, 0);
}

// ---------------------------------------------------------------------------
// GEMM:  C[M,N] = A[M,K] * Bt[N,K]^T  (+bias) (+relu)
// A, Bt bf16 row-major packed (lda=ldbt=K).  C fp32 or bf16, ldc=N.
// 128x128 tile, BK=64, 256 threads = 4 waves (2x2), each wave 64x64.
// m97 structure: global_load_lds width=16 staging, 2-barrier loop.
// ---------------------------------------------------------------------------
template <typename OutT, bool RELU, bool BIAS>
__global__ __launch_bounds__(256, 2) void gemm_bt(
    const u16* __restrict__ A, const u16* __restrict__ Bt,
    OutT* __restrict__ C, const float* __restrict__ bias,
    int N, int K, long sA, long sB, long sC)
{
    A  += (long)blockIdx.z * sA;
    Bt += (long)blockIdx.z * sB;
    C  += (long)blockIdx.z * sC;

    __shared__ u16 As[128 * 64];
    __shared__ u16 Bs[128 * 64];

    const int tid  = threadIdx.x;
    const int lane = tid & 63;
    const int wv   = tid >> 6;
    const int wm   = wv >> 1;   // wave row 0..1
    const int wn   = wv & 1;    // wave col 0..1
    const long row0 = (long)blockIdx.x * 128;
    const long col0 = (long)blockIdx.y * 128;

    f32x4 acc[4][4] = {};

    for (int k0 = 0; k0 < K; k0 += 64) {
        // stage A tile [128][64] and Bt tile [128][64], linear LDS layout
#pragma unroll
        for (int c = 0; c < 4; ++c) {
            const int idx = c * 256 + tid;           // 0..1023
            const int r   = idx >> 3;                // 0..127
            const int cb  = (idx & 7) * 8;           // element col 0..56
            load_lds16(A  + (row0 + r) * K + k0 + cb, &As[idx * 8]);
            load_lds16(Bt + (col0 + r) * K + k0 + cb, &Bs[idx * 8]);
        }
        asm volatile("s_waitcnt vmcnt(0)" ::: "memory");
        __syncthreads();

#pragma unroll
        for (int kk = 0; kk < 2; ++kk) {
            short8 a[4], b[4];
            const int ko = kk * 32 + (lane >> 4) * 8;
#pragma unroll
            for (int m = 0; m < 4; ++m)
                a[m] = *(const short8*)&As[(wm * 64 + m * 16 + (lane & 15)) * 64 + ko];
#pragma unroll
            for (int n = 0; n < 4; ++n)
                b[n] = *(const short8*)&Bs[(wn * 64 + n * 16 + (lane & 15)) * 64 + ko];
#pragma unroll
            for (int m = 0; m < 4; ++m)
#pragma unroll
                for (int n = 0; n < 4; ++n)
                    acc[m][n] = __builtin_amdgcn_mfma_f32_16x16x32_bf16(
                        a[m], b[n], acc[m][n], 0, 0, 0);
        }
        __syncthreads();
    }

    // epilogue: C/D layout col=lane&15, row=(lane>>4)*4+reg
#pragma unroll
    for (int n = 0; n < 4; ++n) {
        const long col = col0 + wn * 64 + n * 16 + (lane & 15);
        const float bv = BIAS ? bias[col] : 0.0f;
#pragma unroll
        for (int m = 0; m < 4; ++m) {
            const long row = row0 + wm * 64 + m * 16 + ((lane >> 4) << 2);
#pragma unroll
            for (int r = 0; r < 4; ++r) {
                float v = acc[m][n][r] + bv;
                if (RELU) v = fmaxf(v, 0.0f);
                if constexpr (sizeof(OutT) == 2)
                    C[(row + r) * N + col] = f2bf(v);
                else
                    C[(row + r) * N + col] = v;
            }
        }
    }
}

// ---------------------------------------------------------------------------
// fp32 [R,C] -> bf16 [C,R] transpose (weights)
// ---------------------------------------------------------------------------
__global__ __launch_bounds__(256) void transpose_cast(
    const float* __restrict__ in, u16* __restrict__ out, int R, int C)
{
    __shared__ float t[32][33];
    const int bc = blockIdx.x * 32, br = blockIdx.y * 32;
    const int lx = threadIdx.x & 31, ly = threadIdx.x >> 5;
#pragma unroll
    for (int i = 0; i < 32; i += 8)
        t[ly + i][lx] = in[(long)(br + ly + i) * C + bc + lx];
    __syncthreads();
#pragma unroll
    for (int i = 0; i < 32; i += 8)
        out[(long)(bc + ly + i) * R + br + lx] = f2bf(t[lx][ly + i]);
}

// bf16 [R,C] -> bf16 [C,R] transpose, batched over z
__global__ __launch_bounds__(256) void transpose_bf(
    const u16* __restrict__ in, u16* __restrict__ out, int R, int C)
{
    __shared__ u16 t[32][33];
    const long zo = (long)blockIdx.z * R * C;
    in += zo; out += zo;
    const int bc = blockIdx.x * 32, br = blockIdx.y * 32;
    const int lx = threadIdx.x & 31, ly = threadIdx.x >> 5;
#pragma unroll
    for (int i = 0; i < 32; i += 8)
        t[ly + i][lx] = in[(long)(br + ly + i) * C + bc + lx];
    __syncthreads();
#pragma unroll
    for (int i = 0; i < 32; i += 8)
        out[(long)(bc + ly + i) * R + br + lx] = t[lx][ly + i];
}

// fp32 -> bf16 elementwise cast, 8 elems/thread
__global__ __launch_bounds__(256) void cast_bf(
    const float* __restrict__ in, u16* __restrict__ out)
{
    const long i = ((long)blockIdx.x * 256 + threadIdx.x) * 8;
    const float4 a = ((const float4*)(in + i))[0];
    const float4 b = ((const float4*)(in + i))[1];
    union { u16 u[8]; uint4 v; } pk;
    pk.u[0] = f2bf(a.x); pk.u[1] = f2bf(a.y); pk.u[2] = f2bf(a.z); pk.u[3] = f2bf(a.w);
    pk.u[4] = f2bf(b.x); pk.u[5] = f2bf(b.y); pk.u[6] = f2bf(b.z); pk.u[7] = f2bf(b.w);
    *(uint4*)(out + i) = pk.v;
}

// ---------------------------------------------------------------------------
// row softmax: fp32 [rows,2048] -> bf16 [rows,2048], one block per row
// ---------------------------------------------------------------------------
__global__ __launch_bounds__(256) void softmax_kernel(
    const float* __restrict__ S, u16* __restrict__ P)
{
    const long row = blockIdx.x;
    const float* src = S + row * SEQ;
    const int tid = threadIdx.x;

    const float4 v0 = ((const float4*)src)[tid * 2];
    const float4 v1 = ((const float4*)src)[tid * 2 + 1];

    float m = fmaxf(fmaxf(fmaxf(v0.x, v0.y), fmaxf(v0.z, v0.w)),
                    fmaxf(fmaxf(v1.x, v1.y), fmaxf(v1.z, v1.w)));
#pragma unroll
    for (int off = 32; off; off >>= 1) m = fmaxf(m, __shfl_xor(m, off));

    __shared__ float rm[4], rs[4];
    if ((tid & 63) == 0) rm[tid >> 6] = m;
    __syncthreads();
    m = fmaxf(fmaxf(rm[0], rm[1]), fmaxf(rm[2], rm[3]));

    float e[8];
    e[0] = expf(v0.x - m); e[1] = expf(v0.y - m);
    e[2] = expf(v0.z - m); e[3] = expf(v0.w - m);
    e[4] = expf(v1.x - m); e[5] = expf(v1.y - m);
    e[6] = expf(v1.z - m); e[7] = expf(v1.w - m);

    float s = ((e[0] + e[1]) + (e[2] + e[3])) + ((e[4] + e[5]) + (e[6] + e[7]));
#pragma unroll
    for (int off = 32; off; off >>= 1) s += __shfl_xor(s, off);
    if ((tid & 63) == 0) rs[tid >> 6] = s;
    __syncthreads();
    s = (rs[0] + rs[1]) + (rs[2] + rs[3]);

    const float inv = 1.0f / s;
    union { u16 u[8]; uint4 v; } pk;
#pragma unroll
    for (int j = 0; j < 8; ++j) pk.u[j] = f2bf(e[j] * inv);
    *(uint4*)(P + row * SEQ + tid * 8) = pk.v;
}

// ---------------------------------------------------------------------------
// fused residual + layernorm: h = A + B; y = (h-mu)*rstd*g + be
// one block (256 thr) per row of 1024.  Writes fp32 Xout and optional bf16 Xb.
// ---------------------------------------------------------------------------
__global__ __launch_bounds__(256) void ln_kernel(
    const float* __restrict__ Ain, const float* __restrict__ Bin,
    const float* __restrict__ g, const float* __restrict__ be,
    float* __restrict__ Xout, u16* __restrict__ Xb)
{
    const long row = blockIdx.x;
    const int tid = threadIdx.x;

    const float4 a = ((const float4*)(Ain + row * EMB))[tid];
    const float4 b = ((const float4*)(Bin + row * EMB))[tid];
    const float h0 = a.x + b.x, h1 = a.y + b.y, h2 = a.z + b.z, h3 = a.w + b.w;

    float s = (h0 + h1) + (h2 + h3);
    float q = (h0 * h0 + h1 * h1) + (h2 * h2 + h3 * h3);
#pragma unroll
    for (int off = 32; off; off >>= 1) {
        s += __shfl_xor(s, off);
        q += __shfl_xor(q, off);
    }
    __shared__ float rsm[4], rqm[4];
    if ((tid & 63) == 0) { rsm[tid >> 6] = s; rqm[tid >> 6] = q; }
    __syncthreads();
    s = (rsm[0] + rsm[1]) + (rsm[2] + rsm[3]);
    q = (rqm[0] + rqm[1]) + (rqm[2] + rqm[3]);

    const float mu  = s * (1.0f / EMB);
    const float var = q * (1.0f / EMB) - mu * mu;
    const float rstd = rsqrtf(var + 1e-5f);

    const float4 gv = ((const float4*)g)[tid];
    const float4 bv = ((const float4*)be)[tid];
    const float y0 = (h0 - mu) * rstd * gv.x + bv.x;
    const float y1 = (h1 - mu) * rstd * gv.y + bv.y;
    const float y2 = (h2 - mu) * rstd * gv.z + bv.z;
    const float y3 = (h3 - mu) * rstd * gv.w + bv.w;

    ((float4*)(Xout + row * EMB))[tid] = make_float4(y0, y1, y2, y3);
    if (Xb) {
        union { u16 u[4]; uint2 v; } pk;
        pk.u[0] = f2bf(y0); pk.u[1] = f2bf(y1);
        pk.u[2] = f2bf(y2); pk.u[3] = f2bf(y3);
        ((uint2*)(Xb + row * EMB))[tid] = pk.v;
    }
}

// ---------------------------------------------------------------------------
extern "C" void kernel_launch(void* const* d_in, const int* in_sizes, int n_in,
                              void* d_out, int out_size, void* d_ws, size_t ws_size,
                              hipStream_t stream)
{
    const float* src = (const float*)d_in[0];
    const float* Wq  = (const float*)d_in[1];
    const float* bq  = (const float*)d_in[2];
    const float* Wk  = (const float*)d_in[3];
    const float* bk  = (const float*)d_in[4];
    const float* Wv  = (const float*)d_in[5];
    const float* bv  = (const float*)d_in[6];
    const float* Wo  = (const float*)d_in[7];
    const float* bo  = (const float*)d_in[8];
    const float* W1  = (const float*)d_in[9];
    const float* b1  = (const float*)d_in[10];
    const float* W2  = (const float*)d_in[11];
    const float* b2  = (const float*)d_in[12];
    const float* g1  = (const float*)d_in[13];
    const float* be1 = (const float*)d_in[14];
    const float* g2  = (const float*)d_in[15];
    const float* be2 = (const float*)d_in[16];
    float* out = (float*)d_out;

    char* ws = (char*)d_ws;
    const size_t MB = 1ull << 20;
    // persistent: transposed bf16 weights [0, 24MiB)
    u16* WqT = (u16*)(ws + 0 * MB);    // [E,E]   2MiB
    u16* WkT = (u16*)(ws + 2 * MB);
    u16* WvT = (u16*)(ws + 4 * MB);
    u16* WoT = (u16*)(ws + 6 * MB);
    u16* W1T = (u16*)(ws + 8 * MB);    // [FF,E]  8MiB
    u16* W2T = (u16*)(ws + 16 * MB);   // [E,FF]  8MiB
    // reuse regions (lifetimes are disjoint in launch order):
    float* scores = (float*)(ws + 24 * MB);   // 64MiB fp32 [B,S,S]
    u16*   ff1    = (u16*)  (ws + 24 * MB);   // 64MiB bf16 [M,FF]   (after softmax)
    u16*   P      = (u16*)  (ws + 88 * MB);   // 32MiB bf16 [B,S,S]
    float* attnp  = (float*)(ws + 88 * MB);   // 32MiB fp32 [M,E]    (after PV)
    float* ff2    = (float*)(ws + 88 * MB);   // 32MiB fp32 [M,E]    (after LN1)
    u16*   Xbf    = (u16*)  (ws + 120 * MB);  // 16MiB bf16 [M,E]
    u16*   Vt     = (u16*)  (ws + 120 * MB);  // 16MiB bf16 [B,E,S]  (after QKV)
    u16*   Qbf    = (u16*)  (ws + 136 * MB);  // 16MiB
    u16*   attn   = (u16*)  (ws + 136 * MB);  // 16MiB bf16 [B,S,E]  (after scores)
    u16*   Kbf    = (u16*)  (ws + 152 * MB);  // 16MiB
    u16*   xbf    = (u16*)  (ws + 152 * MB);  // 16MiB bf16 [M,E]    (after scores)
    u16*   Vbf    = (u16*)  (ws + 168 * MB);  // 16MiB
    float* x      = (float*)(ws + 184 * MB);  // 32MiB fp32 [M,E]
    // total 216 MiB

    const int M = BATCH * SEQ;                  // 8192
    const long SE = (long)SEQ * EMB;            // 2M
    const long SS = (long)SEQ * SEQ;            // 4M

    // 1) weights -> bf16 transposed
    transpose_cast<<<dim3(32, 32, 1), 256, 0, stream>>>(Wq, WqT, EMB, EMB);
    transpose_cast<<<dim3(32, 32, 1), 256, 0, stream>>>(Wk, WkT, EMB, EMB);
    transpose_cast<<<dim3(32, 32, 1), 256, 0, stream>>>(Wv, WvT, EMB, EMB);
    transpose_cast<<<dim3(32, 32, 1), 256, 0, stream>>>(Wo, WoT, EMB, EMB);
    transpose_cast<<<dim3(128, 32, 1), 256, 0, stream>>>(W1, W1T, EMB, FFD);
    transpose_cast<<<dim3(32, 128, 1), 256, 0, stream>>>(W2, W2T, FFD, EMB);

    // 2) src -> bf16
    cast_bf<<<dim3((M * EMB) / (256 * 8)), 256, 0, stream>>>(src, Xbf);

    // 3) Q,K,V projections  [M,E] = [M,E] x [E,E]^T
    gemm_bt<u16, false, true><<<dim3(64, 8, 1), 256, 0, stream>>>(
        Xbf, WqT, Qbf, bq, EMB, EMB, 0, 0, 0);
    gemm_bt<u16, false, true><<<dim3(64, 8, 1), 256, 0, stream>>>(
        Xbf, WkT, Kbf, bk, EMB, EMB, 0, 0, 0);
    gemm_bt<u16, false, true><<<dim3(64, 8, 1), 256, 0, stream>>>(
        Xbf, WvT, Vbf, bv, EMB, EMB, 0, 0, 0);

    // 4) V -> Vt [B,E,S]
    transpose_bf<<<dim3(32, 64, BATCH), 256, 0, stream>>>(Vbf, Vt, SEQ, EMB);

    // 5) scores = Q @ K^T  (per batch)
    gemm_bt<float, false, false><<<dim3(16, 16, BATCH), 256, 0, stream>>>(
        Qbf, Kbf, scores, nullptr, SEQ, EMB, SE, SE, SS);

    // 6) softmax rows -> P bf16
    softmax_kernel<<<dim3(M), 256, 0, stream>>>(scores, P);

    // 7) attn = P @ V   (per batch, Bt = Vt)
    gemm_bt<u16, false, false><<<dim3(16, 8, BATCH), 256, 0, stream>>>(
        P, Vt, attn, nullptr, EMB, SEQ, SS, SE, SE);

    // 8) attnp = attn @ Wo^T + bo
    gemm_bt<float, false, true><<<dim3(64, 8, 1), 256, 0, stream>>>(
        attn, WoT, attnp, bo, EMB, EMB, 0, 0, 0);

    // 9) x = LN1(src + attnp); also xbf
    ln_kernel<<<dim3(M), 256, 0, stream>>>(src, attnp, g1, be1, x, xbf);

    // 10) ff1 = relu(x @ W1^T + b1)
    gemm_bt<u16, true, true><<<dim3(64, 32, 1), 256, 0, stream>>>(
        xbf, W1T, ff1, b1, FFD, EMB, 0, 0, 0);

    // 11) ff2 = ff1 @ W2^T + b2
    gemm_bt<float, false, true><<<dim3(64, 8, 1), 256, 0, stream>>>(
        ff1, W2T, ff2, b2, EMB, FFD, 0, 0, 0);

    // 12) out = LN2(x + ff2)
    ln_kernel<<<dim3(M), 256, 0, stream>>>(x, ff2, g2, be2, out, nullptr);
}

// Round 2
// 434.235 us; speedup vs baseline: 1.1256x; 1.1256x over previous
//
#include <hip/hip_runtime.h>
#include <hip/hip_bf16.h>

// ---------------------------------------------------------------------------
// CustomTransformerLayer: QKV proj -> unscaled single-head attn -> Wo -> LN1
//                         -> FF1(relu) -> FF2 -> LN2
// B=4, S=2048, E=1024, FF=4096.  GEMMs: fp16 MFMA 16x16x32, fp32 acc,
// counted-vmcnt deep pipeline (4-slot LDS ring, 32-wide K slabs, T3+T4+T5).
// ---------------------------------------------------------------------------

using u16 = unsigned short;
typedef __attribute__((ext_vector_type(8))) _Float16 half8;
typedef __attribute__((ext_vector_type(4))) float f32x4;

#define BATCH 4
#define SEQ   2048
#define EMB   1024
#define FFD   4096

// byte-offset swizzle within a [row][64B] slab: spreads 16B slots, 2-way max
#define SWZ(r) ((((r) >> 1) & 3) << 4)

__device__ __forceinline__ u16 f2h(float f) {
    union { _Float16 h; u16 u; } x;
    x.h = (_Float16)f;
    return x.u;
}

typedef const __attribute__((address_space(1))) void* gas_ptr;
typedef __attribute__((address_space(3))) void* las_ptr;

__device__ __forceinline__ void load_lds16(const void* g, void* l) {
    __builtin_amdgcn_global_load_lds((gas_ptr)g, (las_ptr)l, 16, 0, 0);
}

#define VM8 asm volatile("s_waitcnt vmcnt(8)" ::: "memory")
#define VM6 asm volatile("s_waitcnt vmcnt(6)" ::: "memory")
#define VM4 asm volatile("s_waitcnt vmcnt(4)" ::: "memory")
#define VM3 asm volatile("s_waitcnt vmcnt(3)" ::: "memory")
#define VM0 asm volatile("s_waitcnt vmcnt(0)" ::: "memory")
#define VMNONE ((void)0)

// ---------------------------------------------------------------------------
// GEMM:  C[M,N] = A[M,K] * Bt[N,K]^T  (+bias) (+relu)
// A, Bt fp16 (lda/ldb strides). BM x 256 tile, 512 threads = 2x4 waves.
// K consumed in 32-wide slabs through a 4-slot LDS ring, prefetch depth 3.
// ---------------------------------------------------------------------------
template <int BM, typename OutT, bool RELU, bool BIAS>
__global__ __launch_bounds__(512, 2) void gemm_dp(
    const u16* __restrict__ A, const u16* __restrict__ Bt,
    OutT* __restrict__ C, const float* __restrict__ bias,
    int N, int K, int lda, int ldb, int ldc, long sA, long sB, long sC)
{
    constexpr int MF = BM / 32;          // A frags per wave (BM/2 rows / 16)
    constexpr int AL = BM / 128;         // A stage loads per thread per slab
    constexpr int AH = BM * 32;          // elems per A slab
    constexpr int BH = 256 * 32;         // elems per B slab

    __shared__ u16 ldsA[4 * AH];
    __shared__ u16 ldsB[4 * BH];

    A  += (long)blockIdx.z * sA;
    Bt += (long)blockIdx.z * sB;
    C  += (long)blockIdx.z * sC;

    const int tid  = threadIdx.x;
    const int lane = tid & 63;
    const int wv   = tid >> 6;           // 0..7
    const int wm   = wv >> 2;            // 0..1
    const int wn   = wv & 3;             // 0..3
    const long row0 = (long)blockIdx.x * BM;
    const long col0 = (long)blockIdx.y * 256;

    // stage source (global elem offsets) / dest (slab byte offsets) ---------
    long aoff[AL]; int adst[AL];
#pragma unroll
    for (int i = 0; i < AL; ++i) {
        const int d16 = i * 512 + tid;
        const int row = d16 >> 2;
        const int colb = ((d16 & 3) << 4) ^ SWZ(row);   // pre-swizzled source
        aoff[i] = (row0 + row) * (long)lda + (colb >> 1);
        adst[i] = d16 * 16;
    }
    long boff[2]; int bdst[2];
#pragma unroll
    for (int i = 0; i < 2; ++i) {
        const int d16 = i * 512 + tid;
        const int row = d16 >> 2;
        const int colb = ((d16 & 3) << 4) ^ SWZ(row);
        boff[i] = (col0 + row) * (long)ldb + (colb >> 1);
        bdst[i] = d16 * 16;
    }

    // ds_read byte offsets within a slab ------------------------------------
    int aro[MF], bro[4];
    const int klane = (lane >> 4) << 4;  // 0,16,32,48
#pragma unroll
    for (int m = 0; m < MF; ++m) {
        const int row = wm * (BM / 2) + m * 16 + (lane & 15);
        aro[m] = row * 64 + (klane ^ SWZ(row));
    }
#pragma unroll
    for (int n = 0; n < 4; ++n) {
        const int row = wn * 64 + n * 16 + (lane & 15);
        bro[n] = row * 64 + (klane ^ SWZ(row));
    }

    f32x4 acc[MF][4] = {};
    const int G = K >> 5;                // number of 32-wide K slabs

    auto stage = [&](int g) {
        const int slot = g & 3;
        const long k0 = (long)g << 5;
#pragma unroll
        for (int i = 0; i < AL; ++i)
            load_lds16(A + aoff[i] + k0, (char*)ldsA + slot * (AH * 2) + adst[i]);
#pragma unroll
        for (int i = 0; i < 2; ++i)
            load_lds16(Bt + boff[i] + k0, (char*)ldsB + slot * (BH * 2) + bdst[i]);
    };

#define GBODY(g, VMASM, DOSTAGE)                                              \
    {                                                                         \
        const int slot_ = (g) & 3;                                            \
        const char* abase_ = (const char*)ldsA + slot_ * (AH * 2);            \
        const char* bbase_ = (const char*)ldsB + slot_ * (BH * 2);            \
        half8 a_[MF], b_[4];                                                  \
        _Pragma("unroll") for (int m = 0; m < MF; ++m)                        \
            a_[m] = *(const half8*)(abase_ + aro[m]);                         \
        _Pragma("unroll") for (int n = 0; n < 4; ++n)                         \
            b_[n] = *(const half8*)(bbase_ + bro[n]);                         \
        if (DOSTAGE) stage((g) + 3);                                          \
        VMASM;                                                                \
        __builtin_amdgcn_s_setprio(1);                                        \
        _Pragma("unroll") for (int m = 0; m < MF; ++m)                        \
            _Pragma("unroll") for (int n = 0; n < 4; ++n)                     \
                acc[m][n] = __builtin_amdgcn_mfma_f32_16x16x32_f16(           \
                    a_[m], b_[n], acc[m][n], 0, 0, 0);                        \
        __builtin_amdgcn_s_setprio(0);                                        \
        __builtin_amdgcn_s_barrier();                                         \
        __builtin_amdgcn_sched_barrier(0);                                    \
    }

    // prologue: slabs 0,1,2 in flight; wait until slab 0 landed
    stage(0); stage(1); stage(2);
    if constexpr (BM == 256) { VM8; } else { VM6; }
    __builtin_amdgcn_s_barrier();
    __builtin_amdgcn_sched_barrier(0);

    for (int g = 0; g < G - 3; ++g) {
        if constexpr (BM == 256) GBODY(g, VM8, true)
        else                     GBODY(g, VM6, true)
    }
    if constexpr (BM == 256) { GBODY(G - 3, VM4, false) }
    else                     { GBODY(G - 3, VM3, false) }
    GBODY(G - 2, VM0, false)
    GBODY(G - 1, VMNONE, false)
#undef GBODY

    // epilogue: C/D layout col=lane&15, row=(lane>>4)*4+reg
#pragma unroll
    for (int n = 0; n < 4; ++n) {
        const long col = col0 + wn * 64 + n * 16 + (lane & 15);
        const float bv_ = BIAS ? bias[col] : 0.0f;
#pragma unroll
        for (int m = 0; m < MF; ++m) {
            const long row = row0 + wm * (BM / 2) + m * 16 + ((lane >> 4) << 2);
#pragma unroll
            for (int r = 0; r < 4; ++r) {
                float v = acc[m][n][r] + bv_;
                if (RELU) v = fmaxf(v, 0.0f);
                if constexpr (sizeof(OutT) == 2)
                    C[(row + r) * (long)ldc + col] = f2h(v);
                else
                    C[(row + r) * (long)ldc + col] = v;
            }
        }
    }
}

// ---------------------------------------------------------------------------
// fp32 [R,C] -> fp16 [C,R] transpose (weights)
// ---------------------------------------------------------------------------
__global__ __launch_bounds__(256) void transpose_cast(
    const float* __restrict__ in, u16* __restrict__ out, int R, int C)
{
    __shared__ float t[32][33];
    const int bc = blockIdx.x * 32, br = blockIdx.y * 32;
    const int lx = threadIdx.x & 31, ly = threadIdx.x >> 5;
#pragma unroll
    for (int i = 0; i < 32; i += 8)
        t[ly + i][lx] = in[(long)(br + ly + i) * C + bc + lx];
    __syncthreads();
#pragma unroll
    for (int i = 0; i < 32; i += 8)
        out[(long)(bc + ly + i) * R + br + lx] = f2h(t[lx][ly + i]);
}

// fp16 [R,C] (ldin) -> fp16 [C,R] (ldout) transpose, batched over z
__global__ __launch_bounds__(256) void transpose_h(
    const u16* __restrict__ in, u16* __restrict__ out,
    int ldin, int ldout, long sIn, long sOut)
{
    __shared__ u16 t[32][33];
    in  += (long)blockIdx.z * sIn;
    out += (long)blockIdx.z * sOut;
    const int bc = blockIdx.x * 32, br = blockIdx.y * 32;
    const int lx = threadIdx.x & 31, ly = threadIdx.x >> 5;
#pragma unroll
    for (int i = 0; i < 32; i += 8)
        t[ly + i][lx] = in[(long)(br + ly + i) * ldin + bc + lx];
    __syncthreads();
#pragma unroll
    for (int i = 0; i < 32; i += 8)
        out[(long)(bc + ly + i) * ldout + br + lx] = t[lx][ly + i];
}

// fp32 -> fp16 elementwise cast, 8 elems/thread
__global__ __launch_bounds__(256) void cast_h(
    const float* __restrict__ in, u16* __restrict__ out)
{
    const long i = ((long)blockIdx.x * 256 + threadIdx.x) * 8;
    const float4 a = ((const float4*)(in + i))[0];
    const float4 b = ((const float4*)(in + i))[1];
    union { u16 u[8]; uint4 v; } pk;
    pk.u[0] = f2h(a.x); pk.u[1] = f2h(a.y); pk.u[2] = f2h(a.z); pk.u[3] = f2h(a.w);
    pk.u[4] = f2h(b.x); pk.u[5] = f2h(b.y); pk.u[6] = f2h(b.z); pk.u[7] = f2h(b.w);
    *(uint4*)(out + i) = pk.v;
}

// bias concat: [bq|bk|bv] -> 3072 fp32
__global__ __launch_bounds__(256) void concat_bias(
    const float* __restrict__ bq, const float* __restrict__ bk,
    const float* __restrict__ bv, float* __restrict__ o)
{
    const int i = blockIdx.x * 256 + threadIdx.x;
    o[i] = i < 1024 ? bq[i] : (i < 2048 ? bk[i - 1024] : bv[i - 2048]);
}

// ---------------------------------------------------------------------------
// row softmax: fp32 [rows,2048] -> fp16 [rows,2048], one block per row
// ---------------------------------------------------------------------------
__global__ __launch_bounds__(256) void softmax_kernel(
    const float* __restrict__ S, u16* __restrict__ P)
{
    const long row = blockIdx.x;
    const float* src = S + row * SEQ;
    const int tid = threadIdx.x;

    const float4 v0 = ((const float4*)src)[tid * 2];
    const float4 v1 = ((const float4*)src)[tid * 2 + 1];

    float m = fmaxf(fmaxf(fmaxf(v0.x, v0.y), fmaxf(v0.z, v0.w)),
                    fmaxf(fmaxf(v1.x, v1.y), fmaxf(v1.z, v1.w)));
#pragma unroll
    for (int off = 32; off; off >>= 1) m = fmaxf(m, __shfl_xor(m, off));

    __shared__ float rm[4], rs[4];
    if ((tid & 63) == 0) rm[tid >> 6] = m;
    __syncthreads();
    m = fmaxf(fmaxf(rm[0], rm[1]), fmaxf(rm[2], rm[3]));

    float e[8];
    e[0] = expf(v0.x - m); e[1] = expf(v0.y - m);
    e[2] = expf(v0.z - m); e[3] = expf(v0.w - m);
    e[4] = expf(v1.x - m); e[5] = expf(v1.y - m);
    e[6] = expf(v1.z - m); e[7] = expf(v1.w - m);

    float s = ((e[0] + e[1]) + (e[2] + e[3])) + ((e[4] + e[5]) + (e[6] + e[7]));
#pragma unroll
    for (int off = 32; off; off >>= 1) s += __shfl_xor(s, off);
    if ((tid & 63) == 0) rs[tid >> 6] = s;
    __syncthreads();
    s = (rs[0] + rs[1]) + (rs[2] + rs[3]);

    const float inv = 1.0f / s;
    union { u16 u[8]; uint4 v; } pk;
#pragma unroll
    for (int j = 0; j < 8; ++j) pk.u[j] = f2h(e[j] * inv);
    *(uint4*)(P + row * SEQ + tid * 8) = pk.v;
}

// ---------------------------------------------------------------------------
// fused residual + layernorm; writes fp32 Xout and optional fp16 Xh
// ---------------------------------------------------------------------------
__global__ __launch_bounds__(256) void ln_kernel(
    const float* __restrict__ Ain, const float* __restrict__ Bin,
    const float* __restrict__ g, const float* __restrict__ be,
    float* __restrict__ Xout, u16* __restrict__ Xh)
{
    const long row = blockIdx.x;
    const int tid = threadIdx.x;

    const float4 a = ((const float4*)(Ain + row * EMB))[tid];
    const float4 b = ((const float4*)(Bin + row * EMB))[tid];
    const float h0 = a.x + b.x, h1 = a.y + b.y, h2 = a.z + b.z, h3 = a.w + b.w;

    float s = (h0 + h1) + (h2 + h3);
    float q = (h0 * h0 + h1 * h1) + (h2 * h2 + h3 * h3);
#pragma unroll
    for (int off = 32; off; off >>= 1) {
        s += __shfl_xor(s, off);
        q += __shfl_xor(q, off);
    }
    __shared__ float rsm[4], rqm[4];
    if ((tid & 63) == 0) { rsm[tid >> 6] = s; rqm[tid >> 6] = q; }
    __syncthreads();
    s = (rsm[0] + rsm[1]) + (rsm[2] + rsm[3]);
    q = (rqm[0] + rqm[1]) + (rqm[2] + rqm[3]);

    const float mu  = s * (1.0f / EMB);
    const float var = q * (1.0f / EMB) - mu * mu;
    const float rstd = rsqrtf(var + 1e-5f);

    const float4 gv = ((const float4*)g)[tid];
    const float4 bv = ((const float4*)be)[tid];
    const float y0 = (h0 - mu) * rstd * gv.x + bv.x;
    const float y1 = (h1 - mu) * rstd * gv.y + bv.y;
    const float y2 = (h2 - mu) * rstd * gv.z + bv.z;
    const float y3 = (h3 - mu) * rstd * gv.w + bv.w;

    ((float4*)(Xout + row * EMB))[tid] = make_float4(y0, y1, y2, y3);
    if (Xh) {
        union { u16 u[4]; uint2 v; } pk;
        pk.u[0] = f2h(y0); pk.u[1] = f2h(y1);
        pk.u[2] = f2h(y2); pk.u[3] = f2h(y3);
        ((uint2*)(Xh + row * EMB))[tid] = pk.v;
    }
}

// ---------------------------------------------------------------------------
extern "C" void kernel_launch(void* const* d_in, const int* in_sizes, int n_in,
                              void* d_out, int out_size, void* d_ws, size_t ws_size,
                              hipStream_t stream)
{
    const float* src = (const float*)d_in[0];
    const float* Wq  = (const float*)d_in[1];
    const float* bq  = (const float*)d_in[2];
    const float* Wk  = (const float*)d_in[3];
    const float* bk  = (const float*)d_in[4];
    const float* Wv  = (const float*)d_in[5];
    const float* bv  = (const float*)d_in[6];
    const float* Wo  = (const float*)d_in[7];
    const float* bo  = (const float*)d_in[8];
    const float* W1  = (const float*)d_in[9];
    const float* b1  = (const float*)d_in[10];
    const float* W2  = (const float*)d_in[11];
    const float* b2  = (const float*)d_in[12];
    const float* g1  = (const float*)d_in[13];
    const float* be1 = (const float*)d_in[14];
    const float* g2  = (const float*)d_in[15];
    const float* be2 = (const float*)d_in[16];
    float* out = (float*)d_out;

    char* ws = (char*)d_ws;
    const size_t MB = 1ull << 20;
    // persistent fp16 weights
    u16*   WqkvT = (u16*)  (ws + 0 * MB);    // [3072,1024] 6MB
    u16*   WoT   = (u16*)  (ws + 6 * MB);    // [1024,1024] 2MB
    u16*   W1T   = (u16*)  (ws + 8 * MB);    // [4096,1024] 8MB
    u16*   W2T   = (u16*)  (ws + 16 * MB);   // [1024,4096] 8MB
    float* bqkv  = (float*)(ws + 24 * MB);   // [3072]
    u16*   Xh    = (u16*)  (ws + 25 * MB);   // [8192,1024] 16MB
    u16*   QKVh  = (u16*)  (ws + 41 * MB);   // [8192,3072] 48MB
    u16*   Vt    = (u16*)  (ws + 89 * MB);   // [4,1024,2048] 16MB
    float* scores= (float*)(ws + 105 * MB);  // [4,2048,2048] fp32 64MB
    u16*   P     = (u16*)  (ws + 169 * MB);  // [4,2048,2048] fp16 32MB
    u16*   attn  = (u16*)  (ws + 105 * MB);  // 16MB (scores dead after softmax)
    float* attnp = (float*)(ws + 121 * MB);  // 32MB fp32
    u16*   xh    = (u16*)  (ws + 41 * MB);   // 16MB (QKV dead after scores/Vt)
    float* x     = (float*)(ws + 169 * MB);  // 32MB fp32 (P dead after PV)
    u16*   ff1   = (u16*)  (ws + 105 * MB);  // [8192,4096] 64MB (attn/attnp dead)
    float* ff2   = (float*)(ws + 57 * MB);   // 32MB fp32
    // peak: 201MB

    const int M = BATCH * SEQ;                 // 8192
    const long SS = (long)SEQ * SEQ;           // 4M

    // 1) weights -> fp16 transposed (QKV concat into [3072,1024])
    transpose_cast<<<dim3(32, 32, 1), 256, 0, stream>>>(Wq, WqkvT, EMB, EMB);
    transpose_cast<<<dim3(32, 32, 1), 256, 0, stream>>>(Wk, WqkvT + 1024 * 1024, EMB, EMB);
    transpose_cast<<<dim3(32, 32, 1), 256, 0, stream>>>(Wv, WqkvT + 2048 * 1024, EMB, EMB);
    transpose_cast<<<dim3(32, 32, 1), 256, 0, stream>>>(Wo, WoT, EMB, EMB);
    transpose_cast<<<dim3(128, 32, 1), 256, 0, stream>>>(W1, W1T, EMB, FFD);
    transpose_cast<<<dim3(32, 128, 1), 256, 0, stream>>>(W2, W2T, FFD, EMB);
    concat_bias<<<dim3(12), 256, 0, stream>>>(bq, bk, bv, bqkv);

    // 2) src -> fp16
    cast_h<<<dim3((M * EMB) / (256 * 8)), 256, 0, stream>>>(src, Xh);

    // 3) fused QKV projection  [8192,3072]
    gemm_dp<256, u16, false, true><<<dim3(32, 12, 1), 512, 0, stream>>>(
        Xh, WqkvT, QKVh, bqkv, 3072, 1024, 1024, 1024, 3072, 0, 0, 0);

    // 4) V -> Vt [B,E,S]
    transpose_h<<<dim3(32, 64, BATCH), 256, 0, stream>>>(
        QKVh + 2048, Vt, 3072, SEQ, (long)SEQ * 3072, (long)EMB * SEQ);

    // 5) scores = Q @ K^T per batch
    gemm_dp<256, float, false, false><<<dim3(8, 8, BATCH), 512, 0, stream>>>(
        QKVh, QKVh + 1024, scores, nullptr, SEQ, EMB, 3072, 3072, SEQ,
        (long)SEQ * 3072, (long)SEQ * 3072, SS);

    // 6) softmax -> P fp16
    softmax_kernel<<<dim3(M), 256, 0, stream>>>(scores, P);

    // 7) attn = P @ Vt^T per batch
    gemm_dp<128, u16, false, false><<<dim3(16, 4, BATCH), 512, 0, stream>>>(
        P, Vt, attn, nullptr, EMB, SEQ, SEQ, SEQ, EMB,
        SS, (long)EMB * SEQ, (long)SEQ * EMB);

    // 8) attnp = attn @ Wo^T + bo
    gemm_dp<128, float, false, true><<<dim3(64, 4, 1), 512, 0, stream>>>(
        attn, WoT, attnp, bo, EMB, EMB, EMB, EMB, EMB, 0, 0, 0);

    // 9) x = LN1(src + attnp); also xh fp16
    ln_kernel<<<dim3(M), 256, 0, stream>>>(src, attnp, g1, be1, x, xh);

    // 10) ff1 = relu(x @ W1^T + b1)
    gemm_dp<256, u16, true, true><<<dim3(32, 16, 1), 512, 0, stream>>>(
        xh, W1T, ff1, b1, FFD, EMB, EMB, EMB, FFD, 0, 0, 0);

    // 11) ff2 = ff1 @ W2^T + b2
    gemm_dp<128, float, false, true><<<dim3(64, 4, 1), 512, 0, stream>>>(
        ff1, W2T, ff2, b2, EMB, FFD, FFD, FFD, EMB, 0, 0, 0);

    // 12) out = LN2(x + ff2)
    ln_kernel<<<dim3(M), 256, 0, stream>>>(x, ff2, g2, be2, out, nullptr);
}